// Round 1
// baseline (997.677 us; speedup 1.0000x reference)
//
#include <hip/hip_runtime.h>
#include <math.h>

#define SEQL   45000
#define NBAT   2
#define CCH    32
#define NSEL   512
#define NHEAD  4
#define DKD    32
#define HDD    128
#define MLPD   512

// ---------------- K0: basis feature table E[a][16], a = |distance| ----------
// f 0-4: exponential decay; 5-9: central mask; 10-14: normalized gamma pdf.
__global__ void build_etab_kernel(float* __restrict__ E) {
  int a = blockIdx.x * blockDim.x + threadIdx.x;
  if (a >= SEQL) return;
  double ad = (double)a;
  float out[16];
  double log2S = log2((double)SEQL);
  #pragma unroll
  for (int k = 0; k < 5; ++k) {
    double hl = exp2(3.0 + (double)k * (log2S - 3.0) * 0.25);
    out[k] = (float)exp2(-ad / hl);
  }
  const int cw[5] = {1, 3, 7, 15, 31};
  #pragma unroll
  for (int k = 0; k < 5; ++k) out[5 + k] = (a < cw[k]) ? 1.0f : 0.0f;
  double pmax = 0.0;
  double pk[5];
  #pragma unroll
  for (int k = 0; k < 5; ++k) {
    double mean = 9000.0 * (double)(k + 1);
    double sd = 4500.0;
    double cc = (mean / sd) * (mean / sd);      // 4,16,36,64,100
    double rr = mean / (sd * sd);
    double logz = lgamma(cc) - cc * log(rr);
    double p;
    if (a == 0) p = 1e-8;                       // xlogy -> -inf -> exp = 0
    else p = exp((cc - 1.0) * log(ad) - rr * ad - logz) + 1e-8;
    pk[k] = p;
    // unimodal pdf, interior mode -> grid max at floor/ceil of mode
    double mstar = (cc - 1.0) / rr;             // 6750 .. 44550, in range
    double m0 = floor(mstar), m1 = m0 + 1.0;
    if (m1 > (double)(SEQL - 1)) m1 = (double)(SEQL - 1);
    double p0 = exp((cc - 1.0) * log(m0) - rr * m0 - logz) + 1e-8;
    double p1 = exp((cc - 1.0) * log(m1) - rr * m1 - logz) + 1e-8;
    pmax = fmax(pmax, fmax(p0, p1));
  }
  #pragma unroll
  for (int k = 0; k < 5; ++k) out[10 + k] = (float)(pk[k] / pmax);
  out[15] = 0.0f;
  float4* E4 = (float4*)(E + (size_t)a * 16);
  E4[0] = make_float4(out[0], out[1], out[2], out[3]);
  E4[1] = make_float4(out[4], out[5], out[6], out[7]);
  E4[2] = make_float4(out[8], out[9], out[10], out[11]);
  E4[3] = make_float4(out[12], out[13], out[14], out[15]);
}

// ---------------- K1: exact top-256 x2 (radix select) + bitonic sort --------
__global__ __launch_bounds__(512) void topk_kernel(const float* __restrict__ att,
                                                   int* __restrict__ idx) {
  int b = blockIdx.x;
  int tid = threadIdx.x;
  __shared__ int hist[256];
  __shared__ int merged[512];
  __shared__ int eqbuf[2048];
  __shared__ int sh_prefix, sh_want, sh_cgt, sh_ceq;
  for (int ch = 0; ch < 2; ++ch) {
    const float* row = att + ((size_t)b * 3 + 1 + ch) * SEQL;
    unsigned prefix = 0;
    int want = 256;
    for (int pass = 0; pass < 4; ++pass) {
      int shift = 24 - 8 * pass;
      if (tid < 256) hist[tid] = 0;
      __syncthreads();
      for (int i = tid; i < SEQL; i += 512) {
        unsigned key = __float_as_uint(row[i]);   // vals >= 0 -> monotonic bits
        if (pass == 0 || (key >> (shift + 8)) == prefix)
          atomicAdd(&hist[(key >> shift) & 255u], 1);
      }
      __syncthreads();
      if (tid == 0) {
        int acc = 0;
        int v = 255;
        for (;; --v) {
          acc += hist[v];
          if (acc >= want || v == 0) break;
        }
        sh_prefix = (int)((prefix << 8) | (unsigned)v);
        sh_want = want - (acc - hist[v]);
      }
      __syncthreads();
      prefix = (unsigned)sh_prefix;
      want = sh_want;
      __syncthreads();
    }
    // prefix = threshold key T; want = # of ==T elems to take (smallest index)
    if (tid == 0) { sh_cgt = 0; sh_ceq = 0; }
    __syncthreads();
    for (int i = tid; i < SEQL; i += 512) {
      unsigned key = __float_as_uint(row[i]);
      if (key > prefix) {
        int p = atomicAdd(&sh_cgt, 1);
        if (p < 256) merged[ch * 256 + p] = i;
      } else if (key == prefix) {
        int p = atomicAdd(&sh_ceq, 1);
        if (p < 2048) eqbuf[p] = i;
      }
    }
    __syncthreads();
    int ceq = sh_ceq < 2048 ? sh_ceq : 2048;
    for (int i = tid; i < 2048; i += 512)
      if (i >= ceq) eqbuf[i] = 0x7fffffff;
    __syncthreads();
    for (int k = 2; k <= 2048; k <<= 1) {
      for (int j = k >> 1; j > 0; j >>= 1) {
        for (int i = tid; i < 2048; i += 512) {
          int ixj = i ^ j;
          if (ixj > i) {
            int va = eqbuf[i], vb2 = eqbuf[ixj];
            bool up = ((i & k) == 0);
            if ((va > vb2) == up) { eqbuf[i] = vb2; eqbuf[ixj] = va; }
          }
        }
        __syncthreads();
      }
    }
    int cgt = sh_cgt;                 // == 256 - want by construction
    for (int i = tid; i < want; i += 512) merged[ch * 256 + cgt + i] = eqbuf[i];
    __syncthreads();
  }
  // ascending bitonic sort of the 512 merged indices
  for (int k = 2; k <= 512; k <<= 1) {
    for (int j = k >> 1; j > 0; j >>= 1) {
      {
        int i = tid;
        int ixj = i ^ j;
        if (ixj > i) {
          int va = merged[i], vb2 = merged[ixj];
          bool up = ((i & k) == 0);
          if ((va > vb2) == up) { merged[i] = vb2; merged[ixj] = va; }
        }
      }
      __syncthreads();
    }
  }
  idx[b * NSEL + tid] = merged[tid];
}

// ---------------- K2: gather emb rows ---------------------------------------
__global__ void gather_kernel(const float* __restrict__ x, const int* __restrict__ idx,
                              float* __restrict__ emb) {
  int t = blockIdx.x * 256 + threadIdx.x;
  if (t >= NBAT * NSEL * CCH) return;
  int c = t & 31;
  int i = (t >> 5) & 511;
  int b = t >> 14;
  emb[t] = x[((size_t)b * CCH + c) * SEQL + idx[b * NSEL + i]];
}

// ---------------- K3: LN1 + QKV + rel-weight factorization ------------------
__global__ __launch_bounds__(128) void qkv_kernel(
    const float* __restrict__ emb,
    const float* __restrict__ ln_g, const float* __restrict__ ln_b,
    const float* __restrict__ Wq, const float* __restrict__ Wk,
    const float* __restrict__ Wv, const float* __restrict__ Wrel,
    const float* __restrict__ rcb, const float* __restrict__ rpb,
    float* __restrict__ qc, float* __restrict__ kb, float* __restrict__ vb,
    float* __restrict__ wb, int layer) {
  int row = blockIdx.x;        // b*512 + i
  int hd = threadIdx.x;        // 0..127
  const float* e = emb + (size_t)row * CCH;
  float h[32];
  float mu = 0.f;
  #pragma unroll
  for (int c = 0; c < 32; ++c) { h[c] = e[c]; mu += h[c]; }
  mu *= (1.0f / 32.0f);
  float var = 0.f;
  #pragma unroll
  for (int c = 0; c < 32; ++c) { float d = h[c] - mu; var += d * d; }
  var *= (1.0f / 32.0f);
  float rstd = rsqrtf(var + 1e-5f);
  const float* g = ln_g + layer * CCH;
  const float* bb = ln_b + layer * CCH;
  #pragma unroll
  for (int c = 0; c < 32; ++c) h[c] = (h[c] - mu) * rstd * g[c] + bb[c];
  const float* wq = Wq + (size_t)layer * CCH * HDD + hd;
  const float* wk = Wk + (size_t)layer * CCH * HDD + hd;
  const float* wv = Wv + (size_t)layer * CCH * HDD + hd;
  float q = 0.f, kk = 0.f, vv = 0.f;
  #pragma unroll
  for (int c = 0; c < 32; ++c) {
    q += h[c] * wq[c * HDD];
    kk += h[c] * wk[c * HDD];
    vv += h[c] * wv[c * HDD];
  }
  q *= 0.17677669529663687f;   // DK^-0.5
  __shared__ float qs[128];
  qs[hd] = q;
  int hh = hd >> 5, d = hd & 31;
  qc[(size_t)row * HDD + hd] = q + rcb[(layer * NHEAD + hh) * DKD + d];
  kb[(size_t)row * HDD + hd] = kk;
  vb[(size_t)row * HDD + hd] = vv;
  __syncthreads();
  if (hd < 120) {
    int h2 = hd / 30, f = hd % 30;
    const float* wr = Wrel + ((size_t)layer * 30 + f) * HDD + h2 * DKD;
    const float* rp = rpb + (layer * NHEAD + h2) * DKD;
    const float* qsh = qs + h2 * DKD;
    float acc = 0.f;
    #pragma unroll
    for (int dd = 0; dd < 32; ++dd) acc += (qsh[dd] + rp[dd]) * wr[dd];
    wb[((size_t)row * NHEAD + h2) * 32 + f] = acc;   // padded stride 32
  }
}

// ---------------- K4: attention (content + rel + softmax + PV) --------------
// 256 blocks: (b, h, 16 i-rows). 4 waves, each wave: 4 rows (2x2 pairing).
__global__ __launch_bounds__(256) void attn_kernel(
    const float* __restrict__ qc, const float* __restrict__ kb,
    const float* __restrict__ vb, const float* __restrict__ wbuf,
    const float* __restrict__ E, const int* __restrict__ idx,
    float* __restrict__ ob) {
  __shared__ float pb[4096];     // 4 waves x 2 rows x 512 unnormalized probs
  __shared__ int idxl[512];
  int bid = blockIdx.x;
  int b = bid >> 7;
  int h = (bid >> 5) & 3;
  int i0 = (bid & 31) * 16;
  int tid = threadIdx.x;
  int wv = tid >> 6, ln = tid & 63;
  for (int i = tid; i < 512; i += 256) idxl[i] = idx[b * NSEL + i];
  __syncthreads();
  for (int itg = 0; itg < 2; ++itg) {
    int rowA = i0 + wv * 4 + itg * 2;
    float invs[2];
    for (int rr = 0; rr < 2; ++rr) {
      int i = rowA + rr;
      const float* qrow = qc + (size_t)(b * NSEL + i) * HDD + h * DKD;
      float qcr[32];
      #pragma unroll
      for (int d4 = 0; d4 < 8; ++d4) {
        float4 qv = *(const float4*)(qrow + d4 * 4);
        qcr[d4 * 4 + 0] = qv.x; qcr[d4 * 4 + 1] = qv.y;
        qcr[d4 * 4 + 2] = qv.z; qcr[d4 * 4 + 3] = qv.w;
      }
      const float* wrow = wbuf + ((size_t)(b * NSEL + i) * NHEAD + h) * 32;
      float wp[15], wm[15], w0f[15];
      #pragma unroll
      for (int f = 0; f < 15; ++f) {
        float wa = wrow[f], wb2 = wrow[15 + f];
        wp[f] = wa + wb2; wm[f] = wa - wb2; w0f[f] = wa;
      }
      int idxi = idxl[i];
      float lg[8];
      #pragma unroll
      for (int u = 0; u < 8; ++u) {
        int j = ln * 8 + u;                  // lane covers 8 consecutive j
        int dj = idxi - idxl[j];
        int a = dj < 0 ? -dj : dj;
        const float* kr = kb + (size_t)(b * NSEL + j) * HDD + h * DKD;
        float content = 0.f;
        #pragma unroll
        for (int d4 = 0; d4 < 8; ++d4) {
          float4 kv4 = *(const float4*)(kr + d4 * 4);
          content += qcr[d4 * 4 + 0] * kv4.x + qcr[d4 * 4 + 1] * kv4.y
                   + qcr[d4 * 4 + 2] * kv4.z + qcr[d4 * 4 + 3] * kv4.w;
        }
        const float4* er = (const float4*)E + (size_t)a * 4;
        float ev[16];
        *(float4*)(ev + 0)  = er[0];
        *(float4*)(ev + 4)  = er[1];
        *(float4*)(ev + 8)  = er[2];
        *(float4*)(ev + 12) = er[3];
        float rel = 0.f;
        #pragma unroll
        for (int f = 0; f < 15; ++f) {
          float wsel = dj > 0 ? wp[f] : (dj < 0 ? wm[f] : w0f[f]);
          rel += ev[f] * wsel;
        }
        lg[u] = content + rel;
      }
      // full-row softmax across the wave (512 logits, 8/lane)
      float m = lg[0];
      #pragma unroll
      for (int u = 1; u < 8; ++u) m = fmaxf(m, lg[u]);
      #pragma unroll
      for (int s = 1; s < 64; s <<= 1) m = fmaxf(m, __shfl_xor(m, s));
      float ssum = 0.f;
      #pragma unroll
      for (int u = 0; u < 8; ++u) { lg[u] = expf(lg[u] - m); ssum += lg[u]; }
      #pragma unroll
      for (int s = 1; s < 64; s <<= 1) ssum += __shfl_xor(ssum, s);
      invs[rr] = 1.0f / ssum;
      float* pbr = pb + (wv * 2 + rr) * 512 + ln * 8;
      *(float4*)(pbr + 0) = make_float4(lg[0], lg[1], lg[2], lg[3]);
      *(float4*)(pbr + 4) = make_float4(lg[4], lg[5], lg[6], lg[7]);
    }
    __syncthreads();
    // PV for the two rows together (v read once, used twice)
    int d = ln & 31, jh = ln >> 5;
    const float* pA = pb + (wv * 2 + 0) * 512 + jh * 256;
    const float* pB = pb + (wv * 2 + 1) * 512 + jh * 256;
    const float* vbase = vb + (size_t)(b * NSEL + jh * 256) * HDD + h * DKD + d;
    float accA = 0.f, accB = 0.f;
    #pragma unroll 8
    for (int jj = 0; jj < 256; ++jj) {
      float vvv = vbase[(size_t)jj * HDD];
      accA += pA[jj] * vvv;
      accB += pB[jj] * vvv;
    }
    accA += __shfl_xor(accA, 32);
    accB += __shfl_xor(accB, 32);
    if (ln < 32) {
      ob[(size_t)(b * NSEL + rowA) * HDD + h * DKD + d]     = accA * invs[0];
      ob[(size_t)(b * NSEL + rowA + 1) * HDD + h * DKD + d] = accB * invs[1];
    }
    __syncthreads();
  }
}

// ---------------- K5: o @ Wo + bo + residual --------------------------------
__global__ void proj_kernel(const float* __restrict__ ob, const float* __restrict__ Wo,
                            const float* __restrict__ bo, float* __restrict__ emb,
                            int layer) {
  int t = blockIdx.x * 256 + threadIdx.x;
  if (t >= NBAT * NSEL * CCH) return;
  int c = t & 31;
  int row = t >> 5;
  const float* orow = ob + (size_t)row * HDD;
  const float* wo = Wo + (size_t)layer * HDD * CCH + c;
  float acc = bo[layer * CCH + c];
  #pragma unroll 8
  for (int k = 0; k < HDD; ++k) acc += orow[k] * wo[k * CCH];
  emb[t] += acc;
}

// ---------------- K6: LN2 + MLP (exact gelu) + residual ---------------------
__global__ __launch_bounds__(256) void mlp_kernel(
    const float* __restrict__ ln_g, const float* __restrict__ ln_b,
    const float* __restrict__ W1, const float* __restrict__ b1,
    const float* __restrict__ W2, const float* __restrict__ b2,
    float* __restrict__ emb, int layer) {
  __shared__ float a1[512];
  __shared__ float part[8][32];
  int row = blockIdx.x;
  int tid = threadIdx.x;
  float* e = emb + (size_t)row * CCH;
  float h[32];
  float mu = 0.f;
  #pragma unroll
  for (int c = 0; c < 32; ++c) { h[c] = e[c]; mu += h[c]; }
  mu *= (1.0f / 32.0f);
  float var = 0.f;
  #pragma unroll
  for (int c = 0; c < 32; ++c) { float d = h[c] - mu; var += d * d; }
  var *= (1.0f / 32.0f);
  float rstd = rsqrtf(var + 1e-5f);
  const float* g = ln_g + layer * CCH;
  const float* bbv = ln_b + layer * CCH;
  #pragma unroll
  for (int c = 0; c < 32; ++c) h[c] = (h[c] - mu) * rstd * g[c] + bbv[c];
  const float* w1 = W1 + (size_t)layer * CCH * MLPD;
  #pragma unroll
  for (int half = 0; half < 2; ++half) {
    int mm = tid + half * 256;
    float acc = b1[layer * MLPD + mm];
    #pragma unroll
    for (int c = 0; c < 32; ++c) acc += h[c] * w1[c * MLPD + mm];
    a1[mm] = 0.5f * acc * (1.0f + erff(acc * 0.70710678118654752f));
  }
  __syncthreads();
  int c = tid & 31, seg = tid >> 5;
  const float* w2 = W2 + (size_t)layer * MLPD * CCH;
  float acc = 0.f;
  #pragma unroll 8
  for (int m = 0; m < 64; ++m) {
    int mi = seg * 64 + m;
    acc += a1[mi] * w2[mi * CCH + c];
  }
  part[seg][c] = acc;
  __syncthreads();
  if (tid < 32) {
    float s = b2[layer * CCH + tid];
    #pragma unroll
    for (int sg = 0; sg < 8; ++sg) s += part[sg][tid];
    e[tid] += s;
  }
}

// ---------------- K7: scatter back ------------------------------------------
__global__ void scatter_kernel(const float* __restrict__ emb, const int* __restrict__ idx,
                               float* __restrict__ out) {
  int t = blockIdx.x * 256 + threadIdx.x;
  if (t >= NBAT * NSEL * CCH) return;
  int c = t & 31;
  int i = (t >> 5) & 511;
  int b = t >> 14;
  out[((size_t)b * CCH + c) * SEQL + idx[b * NSEL + i]] = emb[t];
}

extern "C" void kernel_launch(void* const* d_in, const int* in_sizes, int n_in,
                              void* d_out, int out_size, void* d_ws, size_t ws_size,
                              hipStream_t stream) {
  (void)in_sizes; (void)n_in; (void)ws_size;
  const float* x_skip    = (const float*)d_in[0];
  const float* attention = (const float*)d_in[1];
  const float* ln1_g = (const float*)d_in[2];
  const float* ln1_b = (const float*)d_in[3];
  const float* Wq    = (const float*)d_in[4];
  const float* Wk    = (const float*)d_in[5];
  const float* Wv    = (const float*)d_in[6];
  const float* Wrel  = (const float*)d_in[7];
  const float* rcb   = (const float*)d_in[8];
  const float* rpb   = (const float*)d_in[9];
  const float* Wo    = (const float*)d_in[10];
  const float* bo    = (const float*)d_in[11];
  const float* ln2_g = (const float*)d_in[12];
  const float* ln2_b = (const float*)d_in[13];
  const float* W1    = (const float*)d_in[14];
  const float* b1    = (const float*)d_in[15];
  const float* W2    = (const float*)d_in[16];
  const float* b2    = (const float*)d_in[17];
  float* out = (float*)d_out;
  char* ws = (char*)d_ws;

  float* E   = (float*)(ws + 0);          // 45000*16*4 = 2,880,000 B
  int*   idx = (int*)(ws + 2880000);      // 4,096 B
  float* emb = (float*)(ws + 2884096);    // 131,072 B
  float* qc  = (float*)(ws + 3015168);    // 524,288 B  (q*scale + rcb)
  float* kb  = (float*)(ws + 3539456);    // 524,288 B
  float* vb  = (float*)(ws + 4063744);    // 524,288 B
  float* wb  = (float*)(ws + 4588032);    // 524,288 B  ((q*scale+rpb)@Wrel^T)
  float* ob  = (float*)(ws + 5112320);    // 524,288 B  -> total 5.64 MB

  hipMemsetAsync(d_out, 0, (size_t)out_size * sizeof(float), stream);
  build_etab_kernel<<<(SEQL + 255) / 256, 256, 0, stream>>>(E);
  topk_kernel<<<2, 512, 0, stream>>>(attention, idx);
  gather_kernel<<<128, 256, 0, stream>>>(x_skip, idx, emb);
  for (int l = 0; l < 4; ++l) {
    qkv_kernel<<<NBAT * NSEL, 128, 0, stream>>>(emb, ln1_g, ln1_b, Wq, Wk, Wv,
                                                Wrel, rcb, rpb, qc, kb, vb, wb, l);
    attn_kernel<<<256, 256, 0, stream>>>(qc, kb, vb, wb, E, idx, ob);
    proj_kernel<<<128, 256, 0, stream>>>(ob, Wo, bo, emb, l);
    mlp_kernel<<<NBAT * NSEL, 256, 0, stream>>>(ln2_g, ln2_b, W1, b1, W2, b2, emb, l);
  }
  scatter_kernel<<<128, 256, 0, stream>>>(emb, idx, out);
}

// Round 2
// 598.586 us; speedup vs baseline: 1.6667x; 1.6667x over previous
//
#include <hip/hip_runtime.h>
#include <math.h>

#define SEQL   45000
#define NBAT   2
#define CCH    32
#define NSEL   512
#define NHEAD  4
#define DKD    32
#define HDD    128
#define MLPD   512
#define TKCAP  2048

// ---------------- K0: basis feature table E[a][16], a = |distance| ----------
// f 0-4: exponential decay; 5-9: central mask; 10-14: normalized gamma pdf.
__global__ void build_etab_kernel(float* __restrict__ E) {
  int a = blockIdx.x * blockDim.x + threadIdx.x;
  if (a >= SEQL) return;
  double ad = (double)a;
  float out[16];
  double log2S = log2((double)SEQL);
  #pragma unroll
  for (int k = 0; k < 5; ++k) {
    double hl = exp2(3.0 + (double)k * (log2S - 3.0) * 0.25);
    out[k] = (float)exp2(-ad / hl);
  }
  const int cw[5] = {1, 3, 7, 15, 31};
  #pragma unroll
  for (int k = 0; k < 5; ++k) out[5 + k] = (a < cw[k]) ? 1.0f : 0.0f;
  double pmax = 0.0;
  double pk[5];
  #pragma unroll
  for (int k = 0; k < 5; ++k) {
    double mean = 9000.0 * (double)(k + 1);
    double sd = 4500.0;
    double cc = (mean / sd) * (mean / sd);      // 4,16,36,64,100
    double rr = mean / (sd * sd);
    double logz = lgamma(cc) - cc * log(rr);
    double p;
    if (a == 0) p = 1e-8;                       // xlogy -> -inf -> exp = 0
    else p = exp((cc - 1.0) * log(ad) - rr * ad - logz) + 1e-8;
    pk[k] = p;
    // unimodal pdf, interior mode -> grid max at floor/ceil of mode
    double mstar = (cc - 1.0) / rr;             // 6750 .. 44550, in range
    double m0 = floor(mstar), m1 = m0 + 1.0;
    if (m1 > (double)(SEQL - 1)) m1 = (double)(SEQL - 1);
    double p0 = exp((cc - 1.0) * log(m0) - rr * m0 - logz) + 1e-8;
    double p1 = exp((cc - 1.0) * log(m1) - rr * m1 - logz) + 1e-8;
    pmax = fmax(pmax, fmax(p0, p1));
  }
  #pragma unroll
  for (int k = 0; k < 5; ++k) out[10 + k] = (float)(pk[k] / pmax);
  out[15] = 0.0f;
  float4* E4 = (float4*)(E + (size_t)a * 16);
  E4[0] = make_float4(out[0], out[1], out[2], out[3]);
  E4[1] = make_float4(out[4], out[5], out[6], out[7]);
  E4[2] = make_float4(out[8], out[9], out[10], out[11]);
  E4[3] = make_float4(out[12], out[13], out[14], out[15]);
}

// ---------------- K1a: exact top-256 per (b, channel) -----------------------
// Radix-select with ballot-aggregated histogram (pass-0 exponent skew would
// serialize LDS atomics ~45000-deep otherwise) + early-exit collect: once the
// candidate class (key >= prefix at current byte granularity) fits in TKCAP,
// collect packed (key<<32)|~idx and one descending bitonic sort gives the
// exact top-256 with value-desc / index-asc tie order.
__global__ __launch_bounds__(1024) void topk_sel_kernel(const float* __restrict__ att,
                                                        unsigned* __restrict__ chsel) {
  int b = blockIdx.x >> 1, ch = blockIdx.x & 1;
  const float* row = att + ((size_t)b * 3 + 1 + ch) * SEQL;
  __shared__ int hist[256];
  __shared__ unsigned long long cand[TKCAP];
  __shared__ int sh_n, sh_v, sh_above, sh_stop;
  int tid = threadIdx.x;
  int lane = tid & 63;
  unsigned prefix = 0;
  int want = 256, cnt_gt = 0, shift = 24;
  const int iters = (SEQL + 1023) / 1024;
  for (int pass = 0; pass < 4; ++pass) {
    shift = 24 - 8 * pass;
    if (tid < 256) hist[tid] = 0;
    __syncthreads();
    for (int it = 0; it < iters; ++it) {
      int i = it * 1024 + tid;
      bool valid = i < SEQL;
      unsigned key = valid ? __float_as_uint(row[i]) : 0u;  // vals >= 0 -> monotone
      if (pass > 0) valid = valid && ((key >> (shift + 8)) == prefix);
      unsigned bucket = (key >> shift) & 255u;
      if (pass == 0) {
        // wave-aggregated: one atomic per distinct bucket per wave
        unsigned long long active = __ballot(valid);
        while (active) {
          int leader = __ffsll(active) - 1;
          unsigned lb = (unsigned)__shfl((int)bucket, leader);
          unsigned long long same = __ballot(valid && bucket == lb);
          if (lane == leader) atomicAdd(&hist[lb], (int)__popcll(same));
          active &= ~same;
        }
      } else if (valid) {
        atomicAdd(&hist[bucket], 1);   // mantissa bits ~uniform: low contention
      }
    }
    __syncthreads();
    if (tid == 0) {
      int acc = 0, v = 255;
      for (;; --v) { acc += hist[v]; if (acc >= want || v == 0) break; }
      sh_v = v;
      sh_above = acc - hist[v];
      sh_stop = (cnt_gt + acc <= TKCAP) ? 1 : 0;
    }
    __syncthreads();
    prefix = (prefix << 8) | (unsigned)sh_v;
    cnt_gt += sh_above;
    want -= sh_above;
    int stop = sh_stop;
    __syncthreads();
    if (stop) break;
  }
  // collect candidates: key >> shift >= prefix  (count in (256..TKCAP])
  if (tid == 0) sh_n = 0;
  __syncthreads();
  for (int i = tid; i < SEQL; i += 1024) {
    unsigned key = __float_as_uint(row[i]);
    if ((key >> shift) >= prefix) {
      int p = atomicAdd(&sh_n, 1);
      if (p < TKCAP) cand[p] = ((unsigned long long)key << 32) | (unsigned)(~(unsigned)i);
    }
  }
  __syncthreads();
  int n = sh_n < TKCAP ? sh_n : TKCAP;
  for (int i = tid; i < TKCAP; i += 1024)
    if (i >= n) cand[i] = 0ull;
  __syncthreads();
  // bitonic sort DESCENDING (value desc; tie -> larger ~i = smaller index first)
  for (int k = 2; k <= TKCAP; k <<= 1) {
    for (int j = k >> 1; j > 0; j >>= 1) {
      for (int i = tid; i < TKCAP; i += 1024) {
        int ixj = i ^ j;
        if (ixj > i) {
          unsigned long long va = cand[i], vb2 = cand[ixj];
          bool up = ((i & k) == 0);
          if ((va < vb2) == up) { cand[i] = vb2; cand[ixj] = va; }
        }
      }
      __syncthreads();
    }
  }
  if (tid < 256)
    chsel[(size_t)blockIdx.x * 256 + tid] = ~(unsigned)(cand[tid] & 0xFFFFFFFFull);
}

// ---------------- K1b: merge acc+don, ascending sort of 512 -----------------
__global__ __launch_bounds__(512) void topk_merge_kernel(const unsigned* __restrict__ chsel,
                                                         int* __restrict__ idx) {
  __shared__ int m[512];
  int b = blockIdx.x, tid = threadIdx.x;
  m[tid] = (int)chsel[(size_t)b * 512 + tid];
  __syncthreads();
  for (int k = 2; k <= 512; k <<= 1) {
    for (int j = k >> 1; j > 0; j >>= 1) {
      int ixj = tid ^ j;
      if (ixj > tid) {
        int va = m[tid], vb2 = m[ixj];
        bool up = ((tid & k) == 0);
        if ((va > vb2) == up) { m[tid] = vb2; m[ixj] = va; }
      }
      __syncthreads();
    }
  }
  idx[b * 512 + tid] = m[tid];
}

// ---------------- K2: gather emb rows ---------------------------------------
__global__ void gather_kernel(const float* __restrict__ x, const int* __restrict__ idx,
                              float* __restrict__ emb) {
  int t = blockIdx.x * 256 + threadIdx.x;
  if (t >= NBAT * NSEL * CCH) return;
  int c = t & 31;
  int i = (t >> 5) & 511;
  int b = t >> 14;
  emb[t] = x[((size_t)b * CCH + c) * SEQL + idx[b * NSEL + i]];
}

// ---------------- K3: LN1 + QKV + rel-weight factorization ------------------
__global__ __launch_bounds__(128) void qkv_kernel(
    const float* __restrict__ emb,
    const float* __restrict__ ln_g, const float* __restrict__ ln_b,
    const float* __restrict__ Wq, const float* __restrict__ Wk,
    const float* __restrict__ Wv, const float* __restrict__ Wrel,
    const float* __restrict__ rcb, const float* __restrict__ rpb,
    float* __restrict__ qc, float* __restrict__ kb, float* __restrict__ vb,
    float* __restrict__ wb, int layer) {
  int row = blockIdx.x;        // b*512 + i
  int hd = threadIdx.x;        // 0..127
  const float* e = emb + (size_t)row * CCH;
  float h[32];
  float mu = 0.f;
  #pragma unroll
  for (int c = 0; c < 32; ++c) { h[c] = e[c]; mu += h[c]; }
  mu *= (1.0f / 32.0f);
  float var = 0.f;
  #pragma unroll
  for (int c = 0; c < 32; ++c) { float d = h[c] - mu; var += d * d; }
  var *= (1.0f / 32.0f);
  float rstd = rsqrtf(var + 1e-5f);
  const float* g = ln_g + layer * CCH;
  const float* bb = ln_b + layer * CCH;
  #pragma unroll
  for (int c = 0; c < 32; ++c) h[c] = (h[c] - mu) * rstd * g[c] + bb[c];
  const float* wq = Wq + (size_t)layer * CCH * HDD + hd;
  const float* wk = Wk + (size_t)layer * CCH * HDD + hd;
  const float* wv = Wv + (size_t)layer * CCH * HDD + hd;
  float q = 0.f, kk = 0.f, vv = 0.f;
  #pragma unroll
  for (int c = 0; c < 32; ++c) {
    q += h[c] * wq[c * HDD];
    kk += h[c] * wk[c * HDD];
    vv += h[c] * wv[c * HDD];
  }
  q *= 0.17677669529663687f;   // DK^-0.5
  __shared__ float qs[128];
  qs[hd] = q;
  int hh = hd >> 5, d = hd & 31;
  qc[(size_t)row * HDD + hd] = q + rcb[(layer * NHEAD + hh) * DKD + d];
  kb[(size_t)row * HDD + hd] = kk;
  vb[(size_t)row * HDD + hd] = vv;
  __syncthreads();
  if (hd < 120) {
    int h2 = hd / 30, f = hd % 30;
    const float* wr = Wrel + ((size_t)layer * 30 + f) * HDD + h2 * DKD;
    const float* rp = rpb + (layer * NHEAD + h2) * DKD;
    const float* qsh = qs + h2 * DKD;
    float acc = 0.f;
    #pragma unroll
    for (int dd = 0; dd < 32; ++dd) acc += (qsh[dd] + rp[dd]) * wr[dd];
    wb[((size_t)row * NHEAD + h2) * 32 + f] = acc;   // padded stride 32
  }
}

// ---------------- K4: attention (content + rel + softmax + PV) --------------
// 512 blocks: (b, h, 8 i-rows). 4 waves/block, each wave owns 2 rows.
// (was 256 blocks = 1 wave/SIMD — no latency hiding for k/E gathers)
__global__ __launch_bounds__(256) void attn_kernel(
    const float* __restrict__ qc, const float* __restrict__ kb,
    const float* __restrict__ vb, const float* __restrict__ wbuf,
    const float* __restrict__ E, const int* __restrict__ idx,
    float* __restrict__ ob) {
  __shared__ float pb[4096];     // 4 waves x 2 rows x 512 unnormalized probs
  __shared__ int idxl[512];
  int bid = blockIdx.x;
  int b = bid >> 8;
  int h = (bid >> 6) & 3;
  int i0 = (bid & 63) * 8;
  int tid = threadIdx.x;
  int wv = tid >> 6, ln = tid & 63;
  for (int i = tid; i < 512; i += 256) idxl[i] = idx[b * NSEL + i];
  __syncthreads();
  int rowA = i0 + wv * 2;
  float invs[2];
  for (int rr = 0; rr < 2; ++rr) {
    int i = rowA + rr;
    const float* qrow = qc + (size_t)(b * NSEL + i) * HDD + h * DKD;
    float qcr[32];
    #pragma unroll
    for (int d4 = 0; d4 < 8; ++d4) {
      float4 qv = *(const float4*)(qrow + d4 * 4);
      qcr[d4 * 4 + 0] = qv.x; qcr[d4 * 4 + 1] = qv.y;
      qcr[d4 * 4 + 2] = qv.z; qcr[d4 * 4 + 3] = qv.w;
    }
    const float* wrow = wbuf + ((size_t)(b * NSEL + i) * NHEAD + h) * 32;
    float wp[15], wm[15], w0f[15];
    #pragma unroll
    for (int f = 0; f < 15; ++f) {
      float wa = wrow[f], wb2 = wrow[15 + f];
      wp[f] = wa + wb2; wm[f] = wa - wb2; w0f[f] = wa;
    }
    int idxi = idxl[i];
    float lg[8];
    #pragma unroll
    for (int u = 0; u < 8; ++u) {
      int j = ln * 8 + u;                  // lane covers 8 consecutive j
      int dj = idxi - idxl[j];
      int a = dj < 0 ? -dj : dj;
      const float* kr = kb + (size_t)(b * NSEL + j) * HDD + h * DKD;
      float content = 0.f;
      #pragma unroll
      for (int d4 = 0; d4 < 8; ++d4) {
        float4 kv4 = *(const float4*)(kr + d4 * 4);
        content += qcr[d4 * 4 + 0] * kv4.x + qcr[d4 * 4 + 1] * kv4.y
                 + qcr[d4 * 4 + 2] * kv4.z + qcr[d4 * 4 + 3] * kv4.w;
      }
      const float4* er = (const float4*)E + (size_t)a * 4;
      float ev[16];
      *(float4*)(ev + 0)  = er[0];
      *(float4*)(ev + 4)  = er[1];
      *(float4*)(ev + 8)  = er[2];
      *(float4*)(ev + 12) = er[3];
      float rel = 0.f;
      #pragma unroll
      for (int f = 0; f < 15; ++f) {
        float wsel = dj > 0 ? wp[f] : (dj < 0 ? wm[f] : w0f[f]);
        rel += ev[f] * wsel;
      }
      lg[u] = content + rel;
    }
    // full-row softmax across the wave (512 logits, 8/lane)
    float m = lg[0];
    #pragma unroll
    for (int u = 1; u < 8; ++u) m = fmaxf(m, lg[u]);
    #pragma unroll
    for (int s = 1; s < 64; s <<= 1) m = fmaxf(m, __shfl_xor(m, s));
    float ssum = 0.f;
    #pragma unroll
    for (int u = 0; u < 8; ++u) { lg[u] = expf(lg[u] - m); ssum += lg[u]; }
    #pragma unroll
    for (int s = 1; s < 64; s <<= 1) ssum += __shfl_xor(ssum, s);
    invs[rr] = 1.0f / ssum;
    float* pbr = pb + (wv * 2 + rr) * 512 + ln * 8;
    *(float4*)(pbr + 0) = make_float4(lg[0], lg[1], lg[2], lg[3]);
    *(float4*)(pbr + 4) = make_float4(lg[4], lg[5], lg[6], lg[7]);
  }
  __syncthreads();
  // PV for the two rows together (v read once, used twice)
  int d = ln & 31, jh = ln >> 5;
  const float* pA = pb + (wv * 2 + 0) * 512 + jh * 256;
  const float* pB = pb + (wv * 2 + 1) * 512 + jh * 256;
  const float* vbase = vb + (size_t)(b * NSEL + jh * 256) * HDD + h * DKD + d;
  float accA = 0.f, accB = 0.f;
  #pragma unroll 8
  for (int jj = 0; jj < 256; ++jj) {
    float vvv = vbase[(size_t)jj * HDD];
    accA += pA[jj] * vvv;
    accB += pB[jj] * vvv;
  }
  accA += __shfl_xor(accA, 32);
  accB += __shfl_xor(accB, 32);
  if (ln < 32) {
    ob[(size_t)(b * NSEL + rowA) * HDD + h * DKD + d]     = accA * invs[0];
    ob[(size_t)(b * NSEL + rowA + 1) * HDD + h * DKD + d] = accB * invs[1];
  }
}

// ---------------- K5: o @ Wo + bo + residual --------------------------------
__global__ void proj_kernel(const float* __restrict__ ob, const float* __restrict__ Wo,
                            const float* __restrict__ bo, float* __restrict__ emb,
                            int layer) {
  int t = blockIdx.x * 256 + threadIdx.x;
  if (t >= NBAT * NSEL * CCH) return;
  int c = t & 31;
  int row = t >> 5;
  const float* orow = ob + (size_t)row * HDD;
  const float* wo = Wo + (size_t)layer * HDD * CCH + c;
  float acc = bo[layer * CCH + c];
  #pragma unroll 8
  for (int k = 0; k < HDD; ++k) acc += orow[k] * wo[k * CCH];
  emb[t] += acc;
}

// ---------------- K6: LN2 + MLP (exact gelu) + residual ---------------------
__global__ __launch_bounds__(256) void mlp_kernel(
    const float* __restrict__ ln_g, const float* __restrict__ ln_b,
    const float* __restrict__ W1, const float* __restrict__ b1,
    const float* __restrict__ W2, const float* __restrict__ b2,
    float* __restrict__ emb, int layer) {
  __shared__ float a1[512];
  __shared__ float part[8][32];
  int row = blockIdx.x;
  int tid = threadIdx.x;
  float* e = emb + (size_t)row * CCH;
  float h[32];
  float mu = 0.f;
  #pragma unroll
  for (int c = 0; c < 32; ++c) { h[c] = e[c]; mu += h[c]; }
  mu *= (1.0f / 32.0f);
  float var = 0.f;
  #pragma unroll
  for (int c = 0; c < 32; ++c) { float d = h[c] - mu; var += d * d; }
  var *= (1.0f / 32.0f);
  float rstd = rsqrtf(var + 1e-5f);
  const float* g = ln_g + layer * CCH;
  const float* bbv = ln_b + layer * CCH;
  #pragma unroll
  for (int c = 0; c < 32; ++c) h[c] = (h[c] - mu) * rstd * g[c] + bbv[c];
  const float* w1 = W1 + (size_t)layer * CCH * MLPD;
  #pragma unroll
  for (int half = 0; half < 2; ++half) {
    int mm = tid + half * 256;
    float acc = b1[layer * MLPD + mm];
    #pragma unroll
    for (int c = 0; c < 32; ++c) acc += h[c] * w1[c * MLPD + mm];
    a1[mm] = 0.5f * acc * (1.0f + erff(acc * 0.70710678118654752f));
  }
  __syncthreads();
  int c = tid & 31, seg = tid >> 5;
  const float* w2 = W2 + (size_t)layer * MLPD * CCH;
  float acc = 0.f;
  #pragma unroll 8
  for (int m = 0; m < 64; ++m) {
    int mi = seg * 64 + m;
    acc += a1[mi] * w2[mi * CCH + c];
  }
  part[seg][c] = acc;
  __syncthreads();
  if (tid < 32) {
    float s = b2[layer * CCH + tid];
    #pragma unroll
    for (int sg = 0; sg < 8; ++sg) s += part[sg][tid];
    e[tid] += s;
  }
}

// ---------------- K7: scatter back ------------------------------------------
__global__ void scatter_kernel(const float* __restrict__ emb, const int* __restrict__ idx,
                               float* __restrict__ out) {
  int t = blockIdx.x * 256 + threadIdx.x;
  if (t >= NBAT * NSEL * CCH) return;
  int c = t & 31;
  int i = (t >> 5) & 511;
  int b = t >> 14;
  out[((size_t)b * CCH + c) * SEQL + idx[b * NSEL + i]] = emb[t];
}

extern "C" void kernel_launch(void* const* d_in, const int* in_sizes, int n_in,
                              void* d_out, int out_size, void* d_ws, size_t ws_size,
                              hipStream_t stream) {
  (void)in_sizes; (void)n_in; (void)ws_size;
  const float* x_skip    = (const float*)d_in[0];
  const float* attention = (const float*)d_in[1];
  const float* ln1_g = (const float*)d_in[2];
  const float* ln1_b = (const float*)d_in[3];
  const float* Wq    = (const float*)d_in[4];
  const float* Wk    = (const float*)d_in[5];
  const float* Wv    = (const float*)d_in[6];
  const float* Wrel  = (const float*)d_in[7];
  const float* rcb   = (const float*)d_in[8];
  const float* rpb   = (const float*)d_in[9];
  const float* Wo    = (const float*)d_in[10];
  const float* bo    = (const float*)d_in[11];
  const float* ln2_g = (const float*)d_in[12];
  const float* ln2_b = (const float*)d_in[13];
  const float* W1    = (const float*)d_in[14];
  const float* b1    = (const float*)d_in[15];
  const float* W2    = (const float*)d_in[16];
  const float* b2    = (const float*)d_in[17];
  float* out = (float*)d_out;
  char* ws = (char*)d_ws;

  float*    E     = (float*)(ws + 0);          // 45000*16*4 = 2,880,000 B
  int*      idx   = (int*)(ws + 2880000);      // 4,096 B
  float*    emb   = (float*)(ws + 2884096);    // 131,072 B
  float*    qc    = (float*)(ws + 3015168);    // 524,288 B  (q*scale + rcb)
  float*    kb    = (float*)(ws + 3539456);    // 524,288 B
  float*    vb    = (float*)(ws + 4063744);    // 524,288 B
  float*    wb    = (float*)(ws + 4588032);    // 524,288 B  ((q*scale+rpb)@Wrel^T)
  float*    ob    = (float*)(ws + 5112320);    // 524,288 B
  unsigned* chsel = (unsigned*)(ws + 5636608); // 4,096 B    -> total 5.64 MB

  hipMemsetAsync(d_out, 0, (size_t)out_size * sizeof(float), stream);
  build_etab_kernel<<<(SEQL + 255) / 256, 256, 0, stream>>>(E);
  topk_sel_kernel<<<4, 1024, 0, stream>>>(attention, chsel);
  topk_merge_kernel<<<2, 512, 0, stream>>>(chsel, idx);
  gather_kernel<<<128, 256, 0, stream>>>(x_skip, idx, emb);
  for (int l = 0; l < 4; ++l) {
    qkv_kernel<<<NBAT * NSEL, 128, 0, stream>>>(emb, ln1_g, ln1_b, Wq, Wk, Wv,
                                                Wrel, rcb, rpb, qc, kb, vb, wb, l);
    attn_kernel<<<512, 256, 0, stream>>>(qc, kb, vb, wb, E, idx, ob);
    proj_kernel<<<128, 256, 0, stream>>>(ob, Wo, bo, emb, l);
    mlp_kernel<<<NBAT * NSEL, 256, 0, stream>>>(ln2_g, ln2_b, W1, b1, W2, b2, emb, l);
  }
  scatter_kernel<<<128, 256, 0, stream>>>(emb, idx, out);
}

// Round 3
// 518.663 us; speedup vs baseline: 1.9236x; 1.1541x over previous
//
#include <hip/hip_runtime.h>
#include <math.h>

#define SEQL   45000
#define NBAT   2
#define CCH    32
#define NSEL   512
#define NHEAD  4
#define DKD    32
#define HDD    128
#define MLPD   512
#define TKCAP  2048
#define TKB    32     // scan blocks per (b,channel)

// ---------------- K0: basis feature table E[a][16], a = |distance| ----------
// fp32 throughout: worst exponent magnitude ~1060 carries ~1e-4 relative
// error through expf — far below the 0.0875 output threshold.
__global__ void build_etab_kernel(float* __restrict__ E) {
  int a = blockIdx.x * blockDim.x + threadIdx.x;
  if (a >= SEQL) return;
  float ad = (float)a;
  float out[16];
  float log2S = log2f((float)SEQL);
  #pragma unroll
  for (int k = 0; k < 5; ++k) {
    float hl = exp2f(3.0f + (float)k * (log2S - 3.0f) * 0.25f);
    out[k] = exp2f(-ad / hl);
  }
  const int cw[5] = {1, 3, 7, 15, 31};
  #pragma unroll
  for (int k = 0; k < 5; ++k) out[5 + k] = (a < cw[k]) ? 1.0f : 0.0f;
  float pmax = 0.0f;
  float pk[5];
  #pragma unroll
  for (int k = 0; k < 5; ++k) {
    float mean = 9000.0f * (float)(k + 1);
    float sd = 4500.0f;
    float cc = (mean / sd) * (mean / sd);      // 4,16,36,64,100
    float rr = mean / (sd * sd);
    float logz = lgammaf(cc) - cc * logf(rr);
    float p;
    if (a == 0) p = 1e-8f;                     // xlogy -> -inf -> exp = 0
    else p = expf((cc - 1.0f) * logf(ad) - rr * ad - logz) + 1e-8f;
    pk[k] = p;
    // unimodal pdf, interior mode -> grid max at floor/ceil of mode
    float mstar = (cc - 1.0f) / rr;            // 6750 .. 44550, in range
    float m0 = floorf(mstar), m1 = m0 + 1.0f;
    if (m1 > (float)(SEQL - 1)) m1 = (float)(SEQL - 1);
    float p0 = expf((cc - 1.0f) * logf(m0) - rr * m0 - logz) + 1e-8f;
    float p1 = expf((cc - 1.0f) * logf(m1) - rr * m1 - logz) + 1e-8f;
    pmax = fmaxf(pmax, fmaxf(p0, p1));
  }
  #pragma unroll
  for (int k = 0; k < 5; ++k) out[10 + k] = pk[k] / pmax;
  out[15] = 0.0f;
  float4* E4 = (float4*)(E + (size_t)a * 16);
  E4[0] = make_float4(out[0], out[1], out[2], out[3]);
  E4[1] = make_float4(out[4], out[5], out[6], out[7]);
  E4[2] = make_float4(out[8], out[9], out[10], out[11]);
  E4[3] = make_float4(out[12], out[13], out[14], out[15]);
}

// ---------------- K1a: distributed 16-bit-key histogram ---------------------
// 128 blocks (4 channels x 32 slices). hist must be pre-zeroed.
__global__ __launch_bounds__(256) void topk_hist_kernel(const float* __restrict__ att,
                                                        int* __restrict__ hist) {
  int ch4 = blockIdx.x / TKB;
  int blk = blockIdx.x % TKB;
  int b = ch4 >> 1, ch = ch4 & 1;
  const float* row = att + ((size_t)b * 3 + 1 + ch) * SEQL;
  int* h = hist + (size_t)ch4 * 65536;
  int per = (SEQL + TKB - 1) / TKB;
  int lo = blk * per;
  int hi = lo + per; if (hi > SEQL) hi = SEQL;
  for (int i = lo + threadIdx.x; i < hi; i += 256)
    atomicAdd(&h[__float_as_uint(row[i]) >> 16], 1);   // vals >= 0 -> monotone
}

// ---------------- K1b: find 16-bit threshold via parallel suffix scan -------
__global__ __launch_bounds__(1024) void topk_thresh_kernel(const int* __restrict__ hist,
                                                           int* __restrict__ thr) {
  const int* h = hist + (size_t)blockIdx.x * 65536;
  __shared__ int s[1024];
  __shared__ int sh_t;
  int t = threadIdx.x;
  int base = t * 64;
  int loc[64];
  int sum = 0;
  #pragma unroll
  for (int i = 0; i < 16; ++i) {
    int4 v = ((const int4*)(h + base))[i];
    loc[i * 4 + 0] = v.x; loc[i * 4 + 1] = v.y;
    loc[i * 4 + 2] = v.z; loc[i * 4 + 3] = v.w;
    sum += v.x + v.y + v.z + v.w;
  }
  s[t] = sum;
  __syncthreads();
  // Hillis-Steele inclusive suffix scan over 1024 chunk sums
  for (int d = 1; d < 1024; d <<= 1) {
    int v = s[t] + ((t + d < 1024) ? s[t + d] : 0);
    __syncthreads();
    s[t] = v;
    __syncthreads();
  }
  int sufEx = (t == 1023) ? 0 : s[t + 1];
  if (s[t] >= 256 && sufEx < 256) sh_t = t;    // unique crossing chunk
  __syncthreads();
  if (t == sh_t) {
    int acc = sufEx;
    int T16 = base;
    for (int i = 63; i >= 0; --i) {
      acc += loc[i];
      if (acc >= 256) { T16 = base + i; break; }
    }
    thr[blockIdx.x] = T16;
  }
}

// ---------------- K1c: distributed candidate collect ------------------------
__global__ __launch_bounds__(256) void topk_collect_kernel(const float* __restrict__ att,
                                                           const int* __restrict__ thr,
                                                           unsigned long long* __restrict__ cand,
                                                           int* __restrict__ cnt) {
  int ch4 = blockIdx.x / TKB;
  int blk = blockIdx.x % TKB;
  int b = ch4 >> 1, ch = ch4 & 1;
  const float* row = att + ((size_t)b * 3 + 1 + ch) * SEQL;
  unsigned T16 = (unsigned)thr[ch4];
  int per = (SEQL + TKB - 1) / TKB;
  int lo = blk * per;
  int hi = lo + per; if (hi > SEQL) hi = SEQL;
  for (int i = lo + threadIdx.x; i < hi; i += 256) {
    unsigned key = __float_as_uint(row[i]);
    if ((key >> 16) >= T16) {
      int p = atomicAdd(&cnt[ch4], 1);
      if (p < TKCAP)
        cand[(size_t)ch4 * TKCAP + p] =
            ((unsigned long long)key << 32) | (unsigned)(~(unsigned)i);
    }
  }
}

// ---------------- K1d: sort candidates desc, emit top-256 -------------------
__global__ __launch_bounds__(1024) void topk_sort_kernel(const unsigned long long* __restrict__ cand,
                                                         const int* __restrict__ cnt,
                                                         unsigned* __restrict__ chsel) {
  __shared__ unsigned long long sc[TKCAP];
  int ch4 = blockIdx.x, t = threadIdx.x;
  int n = cnt[ch4]; if (n > TKCAP) n = TKCAP;
  for (int i = t; i < TKCAP; i += 1024)
    sc[i] = (i < n) ? cand[(size_t)ch4 * TKCAP + i] : 0ull;
  __syncthreads();
  // bitonic DESC (value desc; tie -> larger ~i = smaller index first)
  for (int k = 2; k <= TKCAP; k <<= 1) {
    for (int j = k >> 1; j > 0; j >>= 1) {
      for (int i = t; i < TKCAP; i += 1024) {
        int ixj = i ^ j;
        if (ixj > i) {
          unsigned long long va = sc[i], vb2 = sc[ixj];
          bool up = ((i & k) == 0);
          if ((va < vb2) == up) { sc[i] = vb2; sc[ixj] = va; }
        }
      }
      __syncthreads();
    }
  }
  if (t < 256)
    chsel[(size_t)ch4 * 256 + t] = ~(unsigned)(sc[t] & 0xFFFFFFFFull);
}

// ---------------- K1e: merge acc+don, ascending sort of 512 -----------------
__global__ __launch_bounds__(512) void topk_merge_kernel(const unsigned* __restrict__ chsel,
                                                         int* __restrict__ idx) {
  __shared__ int m[512];
  int b = blockIdx.x, tid = threadIdx.x;
  m[tid] = (int)chsel[(size_t)b * 512 + tid];
  __syncthreads();
  for (int k = 2; k <= 512; k <<= 1) {
    for (int j = k >> 1; j > 0; j >>= 1) {
      int ixj = tid ^ j;
      if (ixj > tid) {
        int va = m[tid], vb2 = m[ixj];
        bool up = ((tid & k) == 0);
        if ((va > vb2) == up) { m[tid] = vb2; m[ixj] = va; }
      }
      __syncthreads();
    }
  }
  idx[b * 512 + tid] = m[tid];
}

// ---------------- K2: gather emb rows ---------------------------------------
__global__ void gather_kernel(const float* __restrict__ x, const int* __restrict__ idx,
                              float* __restrict__ emb) {
  int t = blockIdx.x * 256 + threadIdx.x;
  if (t >= NBAT * NSEL * CCH) return;
  int c = t & 31;
  int i = (t >> 5) & 511;
  int b = t >> 14;
  emb[t] = x[((size_t)b * CCH + c) * SEQL + idx[b * NSEL + i]];
}

// ---------------- K3: LN1 + QKV + rel-weight factorization ------------------
__global__ __launch_bounds__(128) void qkv_kernel(
    const float* __restrict__ emb,
    const float* __restrict__ ln_g, const float* __restrict__ ln_b,
    const float* __restrict__ Wq, const float* __restrict__ Wk,
    const float* __restrict__ Wv, const float* __restrict__ Wrel,
    const float* __restrict__ rcb, const float* __restrict__ rpb,
    float* __restrict__ qc, float* __restrict__ kb, float* __restrict__ vb,
    float* __restrict__ wb, int layer) {
  int row = blockIdx.x;        // b*512 + i
  int hd = threadIdx.x;        // 0..127
  const float* e = emb + (size_t)row * CCH;
  float h[32];
  float mu = 0.f;
  #pragma unroll
  for (int c = 0; c < 32; ++c) { h[c] = e[c]; mu += h[c]; }
  mu *= (1.0f / 32.0f);
  float var = 0.f;
  #pragma unroll
  for (int c = 0; c < 32; ++c) { float d = h[c] - mu; var += d * d; }
  var *= (1.0f / 32.0f);
  float rstd = rsqrtf(var + 1e-5f);
  const float* g = ln_g + layer * CCH;
  const float* bb = ln_b + layer * CCH;
  #pragma unroll
  for (int c = 0; c < 32; ++c) h[c] = (h[c] - mu) * rstd * g[c] + bb[c];
  const float* wq = Wq + (size_t)layer * CCH * HDD + hd;
  const float* wk = Wk + (size_t)layer * CCH * HDD + hd;
  const float* wv = Wv + (size_t)layer * CCH * HDD + hd;
  float q = 0.f, kk = 0.f, vv = 0.f;
  #pragma unroll
  for (int c = 0; c < 32; ++c) {
    q += h[c] * wq[c * HDD];
    kk += h[c] * wk[c * HDD];
    vv += h[c] * wv[c * HDD];
  }
  q *= 0.17677669529663687f;   // DK^-0.5
  __shared__ float qs[128];
  qs[hd] = q;
  int hh = hd >> 5, d = hd & 31;
  qc[(size_t)row * HDD + hd] = q + rcb[(layer * NHEAD + hh) * DKD + d];
  kb[(size_t)row * HDD + hd] = kk;
  vb[(size_t)row * HDD + hd] = vv;
  __syncthreads();
  if (hd < 120) {
    int h2 = hd / 30, f = hd % 30;
    const float* wr = Wrel + ((size_t)layer * 30 + f) * HDD + h2 * DKD;
    const float* rp = rpb + (layer * NHEAD + h2) * DKD;
    const float* qsh = qs + h2 * DKD;
    float acc = 0.f;
    #pragma unroll
    for (int dd = 0; dd < 32; ++dd) acc += (qsh[dd] + rp[dd]) * wr[dd];
    wb[((size_t)row * NHEAD + h2) * 32 + f] = acc;   // padded stride 32
  }
}

// ---------------- K4: attention (content + rel + softmax + PV) --------------
// 512 blocks: (b, h, 8 i-rows). 4 waves/block, each wave owns 2 rows and
// loads each k row ONCE for both (was twice). rel uses
// rel = dot(ev,w0) + sgn*dot(ev,w15), sgn in {-1,0,+1} (sign(d)*e features).
__global__ __launch_bounds__(256) void attn_kernel(
    const float* __restrict__ qc, const float* __restrict__ kb,
    const float* __restrict__ vb, const float* __restrict__ wbuf,
    const float* __restrict__ E, const int* __restrict__ idx,
    float* __restrict__ ob) {
  __shared__ float pb[4096];     // 4 waves x 2 rows x 512 unnormalized probs
  __shared__ int idxl[512];
  int bid = blockIdx.x;
  int b = bid >> 8;
  int h = (bid >> 6) & 3;
  int i0 = (bid & 63) * 8;
  int tid = threadIdx.x;
  int wv = tid >> 6, ln = tid & 63;
  for (int i = tid; i < 512; i += 256) idxl[i] = idx[b * NSEL + i];
  __syncthreads();
  int rowA = i0 + wv * 2;
  const float* qra = qc + (size_t)(b * NSEL + rowA) * HDD + h * DKD;
  const float* qrb = qra + HDD;
  float qA[32], qB[32];
  #pragma unroll
  for (int d4 = 0; d4 < 8; ++d4) {
    float4 va = *(const float4*)(qra + d4 * 4);
    float4 vb4 = *(const float4*)(qrb + d4 * 4);
    qA[d4 * 4 + 0] = va.x;  qA[d4 * 4 + 1] = va.y;
    qA[d4 * 4 + 2] = va.z;  qA[d4 * 4 + 3] = va.w;
    qB[d4 * 4 + 0] = vb4.x; qB[d4 * 4 + 1] = vb4.y;
    qB[d4 * 4 + 2] = vb4.z; qB[d4 * 4 + 3] = vb4.w;
  }
  const float* wra = wbuf + ((size_t)(b * NSEL + rowA) * NHEAD + h) * 32;
  const float* wrb = wra + NHEAD * 32;
  float w0A[15], w1A[15], w0B[15], w1B[15];
  #pragma unroll
  for (int f = 0; f < 15; ++f) {
    w0A[f] = wra[f]; w1A[f] = wra[15 + f];
    w0B[f] = wrb[f]; w1B[f] = wrb[15 + f];
  }
  int ia = idxl[rowA], ib2 = idxl[rowA + 1];
  float lgA[8], lgB[8];
  #pragma unroll
  for (int u = 0; u < 8; ++u) {
    int j = ln * 8 + u;
    int ij = idxl[j];
    const float* kr = kb + (size_t)(b * NSEL + j) * HDD + h * DKD;
    float cA = 0.f, cB = 0.f;
    #pragma unroll
    for (int d4 = 0; d4 < 8; ++d4) {
      float4 kv = *(const float4*)(kr + d4 * 4);
      cA += qA[d4 * 4 + 0] * kv.x + qA[d4 * 4 + 1] * kv.y
          + qA[d4 * 4 + 2] * kv.z + qA[d4 * 4 + 3] * kv.w;
      cB += qB[d4 * 4 + 0] * kv.x + qB[d4 * 4 + 1] * kv.y
          + qB[d4 * 4 + 2] * kv.z + qB[d4 * 4 + 3] * kv.w;
    }
    int dA = ia - ij, dB = ib2 - ij;
    {
      int a = dA < 0 ? -dA : dA;
      const float4* er = (const float4*)E + (size_t)a * 4;
      float ev[16];
      *(float4*)(ev + 0)  = er[0];
      *(float4*)(ev + 4)  = er[1];
      *(float4*)(ev + 8)  = er[2];
      *(float4*)(ev + 12) = er[3];
      float r0 = 0.f, r1 = 0.f;
      #pragma unroll
      for (int f = 0; f < 15; ++f) { r0 += ev[f] * w0A[f]; r1 += ev[f] * w1A[f]; }
      float sgn = dA > 0 ? 1.f : (dA < 0 ? -1.f : 0.f);
      lgA[u] = cA + r0 + sgn * r1;
    }
    {
      int a = dB < 0 ? -dB : dB;
      const float4* er = (const float4*)E + (size_t)a * 4;
      float ev[16];
      *(float4*)(ev + 0)  = er[0];
      *(float4*)(ev + 4)  = er[1];
      *(float4*)(ev + 8)  = er[2];
      *(float4*)(ev + 12) = er[3];
      float r0 = 0.f, r1 = 0.f;
      #pragma unroll
      for (int f = 0; f < 15; ++f) { r0 += ev[f] * w0B[f]; r1 += ev[f] * w1B[f]; }
      float sgn = dB > 0 ? 1.f : (dB < 0 ? -1.f : 0.f);
      lgB[u] = cB + r0 + sgn * r1;
    }
  }
  float invs[2];
  {
    float m = lgA[0];
    #pragma unroll
    for (int u = 1; u < 8; ++u) m = fmaxf(m, lgA[u]);
    #pragma unroll
    for (int s = 1; s < 64; s <<= 1) m = fmaxf(m, __shfl_xor(m, s));
    float ssum = 0.f;
    #pragma unroll
    for (int u = 0; u < 8; ++u) { lgA[u] = expf(lgA[u] - m); ssum += lgA[u]; }
    #pragma unroll
    for (int s = 1; s < 64; s <<= 1) ssum += __shfl_xor(ssum, s);
    invs[0] = 1.0f / ssum;
    float* pbr = pb + (wv * 2 + 0) * 512 + ln * 8;
    *(float4*)(pbr + 0) = make_float4(lgA[0], lgA[1], lgA[2], lgA[3]);
    *(float4*)(pbr + 4) = make_float4(lgA[4], lgA[5], lgA[6], lgA[7]);
  }
  {
    float m = lgB[0];
    #pragma unroll
    for (int u = 1; u < 8; ++u) m = fmaxf(m, lgB[u]);
    #pragma unroll
    for (int s = 1; s < 64; s <<= 1) m = fmaxf(m, __shfl_xor(m, s));
    float ssum = 0.f;
    #pragma unroll
    for (int u = 0; u < 8; ++u) { lgB[u] = expf(lgB[u] - m); ssum += lgB[u]; }
    #pragma unroll
    for (int s = 1; s < 64; s <<= 1) ssum += __shfl_xor(ssum, s);
    invs[1] = 1.0f / ssum;
    float* pbr = pb + (wv * 2 + 1) * 512 + ln * 8;
    *(float4*)(pbr + 0) = make_float4(lgB[0], lgB[1], lgB[2], lgB[3]);
    *(float4*)(pbr + 4) = make_float4(lgB[4], lgB[5], lgB[6], lgB[7]);
  }
  __syncthreads();
  // PV for the two rows together (v read once, used twice)
  int d = ln & 31, jh = ln >> 5;
  const float* pA = pb + (wv * 2 + 0) * 512 + jh * 256;
  const float* pB = pb + (wv * 2 + 1) * 512 + jh * 256;
  const float* vbase = vb + (size_t)(b * NSEL + jh * 256) * HDD + h * DKD + d;
  float accA = 0.f, accB = 0.f;
  #pragma unroll 8
  for (int jj = 0; jj < 256; ++jj) {
    float vvv = vbase[(size_t)jj * HDD];
    accA += pA[jj] * vvv;
    accB += pB[jj] * vvv;
  }
  accA += __shfl_xor(accA, 32);
  accB += __shfl_xor(accB, 32);
  if (ln < 32) {
    ob[(size_t)(b * NSEL + rowA) * HDD + h * DKD + d]     = accA * invs[0];
    ob[(size_t)(b * NSEL + rowA + 1) * HDD + h * DKD + d] = accB * invs[1];
  }
}

// ---------------- K5: fused (o @ Wo + bo + residual) + LN2 + MLP + residual -
__global__ __launch_bounds__(256) void mlp_kernel(
    const float* __restrict__ ob, const float* __restrict__ Wo,
    const float* __restrict__ bo,
    const float* __restrict__ ln_g, const float* __restrict__ ln_b,
    const float* __restrict__ W1, const float* __restrict__ b1,
    const float* __restrict__ W2, const float* __restrict__ b2,
    float* __restrict__ emb, int layer) {
  __shared__ float a1[512];
  __shared__ float part[8][32];
  __shared__ float r[32];
  int row = blockIdx.x;
  int tid = threadIdx.x;
  int c = tid & 31, seg = tid >> 5;
  // --- attention out-projection: part[seg][c] over k = seg*16..+16
  const float* orow = ob + (size_t)row * HDD;
  const float* wo = Wo + (size_t)layer * HDD * CCH + c;
  float pacc = 0.f;
  #pragma unroll
  for (int k = 0; k < 16; ++k) {
    int kk = seg * 16 + k;
    pacc += orow[kk] * wo[kk * CCH];
  }
  part[seg][c] = pacc;
  __syncthreads();
  if (tid < 32) {
    float s = bo[layer * CCH + tid] + emb[(size_t)row * CCH + tid];
    #pragma unroll
    for (int sg = 0; sg < 8; ++sg) s += part[sg][tid];
    r[tid] = s;                       // post-attention residual
  }
  __syncthreads();
  // --- LN2 over r (LDS broadcast reads)
  float h[32];
  float mu = 0.f;
  #pragma unroll
  for (int cc2 = 0; cc2 < 32; ++cc2) { h[cc2] = r[cc2]; mu += h[cc2]; }
  mu *= (1.0f / 32.0f);
  float var = 0.f;
  #pragma unroll
  for (int cc2 = 0; cc2 < 32; ++cc2) { float d = h[cc2] - mu; var += d * d; }
  var *= (1.0f / 32.0f);
  float rstd = rsqrtf(var + 1e-5f);
  const float* g = ln_g + layer * CCH;
  const float* bbv = ln_b + layer * CCH;
  #pragma unroll
  for (int cc2 = 0; cc2 < 32; ++cc2) h[cc2] = (h[cc2] - mu) * rstd * g[cc2] + bbv[cc2];
  const float* w1 = W1 + (size_t)layer * CCH * MLPD;
  #pragma unroll
  for (int half = 0; half < 2; ++half) {
    int mm = tid + half * 256;
    float acc = b1[layer * MLPD + mm];
    #pragma unroll
    for (int cc2 = 0; cc2 < 32; ++cc2) acc += h[cc2] * w1[cc2 * MLPD + mm];
    a1[mm] = 0.5f * acc * (1.0f + erff(acc * 0.70710678118654752f));
  }
  __syncthreads();
  const float* w2 = W2 + (size_t)layer * MLPD * CCH;
  float acc = 0.f;
  #pragma unroll 8
  for (int m = 0; m < 64; ++m) {
    int mi = seg * 64 + m;
    acc += a1[mi] * w2[mi * CCH + c];
  }
  __syncthreads();                    // part[] reuse
  part[seg][c] = acc;
  __syncthreads();
  if (tid < 32) {
    float s = b2[layer * CCH + tid] + r[tid];
    #pragma unroll
    for (int sg = 0; sg < 8; ++sg) s += part[sg][tid];
    emb[(size_t)row * CCH + tid] = s;
  }
}

// ---------------- K7: scatter back ------------------------------------------
__global__ void scatter_kernel(const float* __restrict__ emb, const int* __restrict__ idx,
                               float* __restrict__ out) {
  int t = blockIdx.x * 256 + threadIdx.x;
  if (t >= NBAT * NSEL * CCH) return;
  int c = t & 31;
  int i = (t >> 5) & 511;
  int b = t >> 14;
  out[((size_t)b * CCH + c) * SEQL + idx[b * NSEL + i]] = emb[t];
}

extern "C" void kernel_launch(void* const* d_in, const int* in_sizes, int n_in,
                              void* d_out, int out_size, void* d_ws, size_t ws_size,
                              hipStream_t stream) {
  (void)in_sizes; (void)n_in; (void)ws_size;
  const float* x_skip    = (const float*)d_in[0];
  const float* attention = (const float*)d_in[1];
  const float* ln1_g = (const float*)d_in[2];
  const float* ln1_b = (const float*)d_in[3];
  const float* Wq    = (const float*)d_in[4];
  const float* Wk    = (const float*)d_in[5];
  const float* Wv    = (const float*)d_in[6];
  const float* Wrel  = (const float*)d_in[7];
  const float* rcb   = (const float*)d_in[8];
  const float* rpb   = (const float*)d_in[9];
  const float* Wo    = (const float*)d_in[10];
  const float* bo    = (const float*)d_in[11];
  const float* ln2_g = (const float*)d_in[12];
  const float* ln2_b = (const float*)d_in[13];
  const float* W1    = (const float*)d_in[14];
  const float* b1    = (const float*)d_in[15];
  const float* W2    = (const float*)d_in[16];
  const float* b2    = (const float*)d_in[17];
  float* out = (float*)d_out;
  char* ws = (char*)d_ws;

  float*    E     = (float*)(ws + 0);          // 2,880,000 B
  int*      idx   = (int*)(ws + 2880000);      // 4,096 B
  float*    emb   = (float*)(ws + 2884096);    // 131,072 B
  float*    qc    = (float*)(ws + 3015168);    // 524,288 B
  float*    kb    = (float*)(ws + 3539456);    // 524,288 B
  float*    vb    = (float*)(ws + 4063744);    // 524,288 B
  float*    wb    = (float*)(ws + 4588032);    // 524,288 B
  float*    ob    = (float*)(ws + 5112320);    // 524,288 B
  unsigned* chsel = (unsigned*)(ws + 5636608); // 4,096 B
  int*      hist  = (int*)(ws + 5640704);      // 4*65536*4 = 1,048,576 B
  int*      cnt   = (int*)(ws + 6689280);      // 16 B
  unsigned long long* cand = (unsigned long long*)(ws + 6689296); // 65,536 B
  int*      thr   = (int*)(ws + 6754832);      // 16 B  -> total ~6.75 MB

  hipMemsetAsync(d_out, 0, (size_t)out_size * sizeof(float), stream);
  hipMemsetAsync(ws + 5640704, 0, 1048576 + 16, stream);   // hist + cnt
  build_etab_kernel<<<(SEQL + 255) / 256, 256, 0, stream>>>(E);
  topk_hist_kernel<<<4 * TKB, 256, 0, stream>>>(attention, hist);
  topk_thresh_kernel<<<4, 1024, 0, stream>>>(hist, thr);
  topk_collect_kernel<<<4 * TKB, 256, 0, stream>>>(attention, thr, cand, cnt);
  topk_sort_kernel<<<4, 1024, 0, stream>>>(cand, cnt, chsel);
  topk_merge_kernel<<<2, 512, 0, stream>>>(chsel, idx);
  gather_kernel<<<128, 256, 0, stream>>>(x_skip, idx, emb);
  for (int l = 0; l < 4; ++l) {
    qkv_kernel<<<NBAT * NSEL, 128, 0, stream>>>(emb, ln1_g, ln1_b, Wq, Wk, Wv,
                                                Wrel, rcb, rpb, qc, kb, vb, wb, l);
    attn_kernel<<<512, 256, 0, stream>>>(qc, kb, vb, wb, E, idx, ob);
    mlp_kernel<<<NBAT * NSEL, 256, 0, stream>>>(ob, Wo, bo, ln2_g, ln2_b,
                                                W1, b1, W2, b2, emb, l);
  }
  scatter_kernel<<<128, 256, 0, stream>>>(emb, idx, out);
}

// Round 4
// 378.572 us; speedup vs baseline: 2.6354x; 1.3701x over previous
//
#include <hip/hip_runtime.h>
#include <math.h>

#define SEQL   45000
#define NBAT   2
#define CCH    32
#define NSEL   512
#define NHEAD  4
#define DKD    32
#define HDD    128
#define MLPD   512
#define TKCAP  2048
#define TKB    32     // scan blocks per (b,channel)

// bf16 helpers: round-to-nearest-even pack, cheap unpack (<<16)
__device__ inline unsigned short f2bf(float x) {
  unsigned u = __float_as_uint(x);
  u = (u + 0x7fffu + ((u >> 16) & 1u)) >> 16;
  return (unsigned short)u;
}
#define BFL(u) __uint_as_float((u) << 16)
#define BFH(u) __uint_as_float((u) & 0xffff0000u)
__device__ inline float bf2f(unsigned short s) {
  return __uint_as_float(((unsigned)s) << 16);
}

// ---------------- K0: basis feature table E[a][16] in bf16 ------------------
// f 0-4: exponential decay; 5-9: central mask; 10-14: normalized gamma pdf.
__global__ void build_etab_kernel(unsigned short* __restrict__ E) {
  int a = blockIdx.x * blockDim.x + threadIdx.x;
  if (a >= SEQL) return;
  float ad = (float)a;
  float out[16];
  float log2S = log2f((float)SEQL);
  #pragma unroll
  for (int k = 0; k < 5; ++k) {
    float hl = exp2f(3.0f + (float)k * (log2S - 3.0f) * 0.25f);
    out[k] = exp2f(-ad / hl);
  }
  const int cw[5] = {1, 3, 7, 15, 31};
  #pragma unroll
  for (int k = 0; k < 5; ++k) out[5 + k] = (a < cw[k]) ? 1.0f : 0.0f;
  float pmax = 0.0f;
  float pk[5];
  #pragma unroll
  for (int k = 0; k < 5; ++k) {
    float mean = 9000.0f * (float)(k + 1);
    float sd = 4500.0f;
    float cc = (mean / sd) * (mean / sd);      // 4,16,36,64,100
    float rr = mean / (sd * sd);
    float logz = lgammaf(cc) - cc * logf(rr);
    float p;
    if (a == 0) p = 1e-8f;                     // xlogy -> -inf -> exp = 0
    else p = expf((cc - 1.0f) * logf(ad) - rr * ad - logz) + 1e-8f;
    pk[k] = p;
    // unimodal pdf, interior mode -> grid max at floor/ceil of mode
    float mstar = (cc - 1.0f) / rr;            // 6750 .. 44550, in range
    float m0 = floorf(mstar), m1 = m0 + 1.0f;
    if (m1 > (float)(SEQL - 1)) m1 = (float)(SEQL - 1);
    float p0 = expf((cc - 1.0f) * logf(m0) - rr * m0 - logz) + 1e-8f;
    float p1 = expf((cc - 1.0f) * logf(m1) - rr * m1 - logz) + 1e-8f;
    pmax = fmaxf(pmax, fmaxf(p0, p1));
  }
  #pragma unroll
  for (int k = 0; k < 5; ++k) out[10 + k] = pk[k] / pmax;
  out[15] = 0.0f;
  uint4 o0, o1;
  o0.x = (unsigned)f2bf(out[0])  | ((unsigned)f2bf(out[1])  << 16);
  o0.y = (unsigned)f2bf(out[2])  | ((unsigned)f2bf(out[3])  << 16);
  o0.z = (unsigned)f2bf(out[4])  | ((unsigned)f2bf(out[5])  << 16);
  o0.w = (unsigned)f2bf(out[6])  | ((unsigned)f2bf(out[7])  << 16);
  o1.x = (unsigned)f2bf(out[8])  | ((unsigned)f2bf(out[9])  << 16);
  o1.y = (unsigned)f2bf(out[10]) | ((unsigned)f2bf(out[11]) << 16);
  o1.z = (unsigned)f2bf(out[12]) | ((unsigned)f2bf(out[13]) << 16);
  o1.w = (unsigned)f2bf(out[14]);
  uint4* E4 = (uint4*)(E + (size_t)a * 16);
  E4[0] = o0;
  E4[1] = o1;
}

// ---------------- K1a: distributed 16-bit-key histogram ---------------------
__global__ __launch_bounds__(256) void topk_hist_kernel(const float* __restrict__ att,
                                                        int* __restrict__ hist) {
  int ch4 = blockIdx.x / TKB;
  int blk = blockIdx.x % TKB;
  int b = ch4 >> 1, ch = ch4 & 1;
  const float* row = att + ((size_t)b * 3 + 1 + ch) * SEQL;
  int* h = hist + (size_t)ch4 * 65536;
  int per = (SEQL + TKB - 1) / TKB;
  int lo = blk * per;
  int hi = lo + per; if (hi > SEQL) hi = SEQL;
  for (int i = lo + threadIdx.x; i < hi; i += 256)
    atomicAdd(&h[__float_as_uint(row[i]) >> 16], 1);   // vals >= 0 -> monotone
}

// ---------------- K1b: find 16-bit threshold via parallel suffix scan -------
__global__ __launch_bounds__(1024) void topk_thresh_kernel(const int* __restrict__ hist,
                                                           int* __restrict__ thr) {
  const int* h = hist + (size_t)blockIdx.x * 65536;
  __shared__ int s[1024];
  __shared__ int sh_t;
  int t = threadIdx.x;
  int base = t * 64;
  int loc[64];
  int sum = 0;
  #pragma unroll
  for (int i = 0; i < 16; ++i) {
    int4 v = ((const int4*)(h + base))[i];
    loc[i * 4 + 0] = v.x; loc[i * 4 + 1] = v.y;
    loc[i * 4 + 2] = v.z; loc[i * 4 + 3] = v.w;
    sum += v.x + v.y + v.z + v.w;
  }
  s[t] = sum;
  __syncthreads();
  for (int d = 1; d < 1024; d <<= 1) {
    int v = s[t] + ((t + d < 1024) ? s[t + d] : 0);
    __syncthreads();
    s[t] = v;
    __syncthreads();
  }
  int sufEx = (t == 1023) ? 0 : s[t + 1];
  if (s[t] >= 256 && sufEx < 256) sh_t = t;    // unique crossing chunk
  __syncthreads();
  if (t == sh_t) {
    int acc = sufEx;
    int T16 = base;
    for (int i = 63; i >= 0; --i) {
      acc += loc[i];
      if (acc >= 256) { T16 = base + i; break; }
    }
    thr[blockIdx.x] = T16;
  }
}

// ---------------- K1c: distributed candidate collect ------------------------
__global__ __launch_bounds__(256) void topk_collect_kernel(const float* __restrict__ att,
                                                           const int* __restrict__ thr,
                                                           unsigned long long* __restrict__ cand,
                                                           int* __restrict__ cnt) {
  int ch4 = blockIdx.x / TKB;
  int blk = blockIdx.x % TKB;
  int b = ch4 >> 1, ch = ch4 & 1;
  const float* row = att + ((size_t)b * 3 + 1 + ch) * SEQL;
  unsigned T16 = (unsigned)thr[ch4];
  int per = (SEQL + TKB - 1) / TKB;
  int lo = blk * per;
  int hi = lo + per; if (hi > SEQL) hi = SEQL;
  for (int i = lo + threadIdx.x; i < hi; i += 256) {
    unsigned key = __float_as_uint(row[i]);
    if ((key >> 16) >= T16) {
      int p = atomicAdd(&cnt[ch4], 1);
      if (p < TKCAP)
        cand[(size_t)ch4 * TKCAP + p] =
            ((unsigned long long)key << 32) | (unsigned)(~(unsigned)i);
    }
  }
}

// ---------------- K1d: sort candidates desc, emit top-256 -------------------
__global__ __launch_bounds__(1024) void topk_sort_kernel(const unsigned long long* __restrict__ cand,
                                                         const int* __restrict__ cnt,
                                                         unsigned* __restrict__ chsel) {
  __shared__ unsigned long long sc[TKCAP];
  int ch4 = blockIdx.x, t = threadIdx.x;
  int n = cnt[ch4]; if (n > TKCAP) n = TKCAP;
  for (int i = t; i < TKCAP; i += 1024)
    sc[i] = (i < n) ? cand[(size_t)ch4 * TKCAP + i] : 0ull;
  __syncthreads();
  for (int k = 2; k <= TKCAP; k <<= 1) {
    for (int j = k >> 1; j > 0; j >>= 1) {
      for (int i = t; i < TKCAP; i += 1024) {
        int ixj = i ^ j;
        if (ixj > i) {
          unsigned long long va = sc[i], vb2 = sc[ixj];
          bool up = ((i & k) == 0);
          if ((va < vb2) == up) { sc[i] = vb2; sc[ixj] = va; }
        }
      }
      __syncthreads();
    }
  }
  if (t < 256)
    chsel[(size_t)ch4 * 256 + t] = ~(unsigned)(sc[t] & 0xFFFFFFFFull);
}

// ---------------- K1e: merge acc+don, ascending sort of 512 -----------------
__global__ __launch_bounds__(512) void topk_merge_kernel(const unsigned* __restrict__ chsel,
                                                         int* __restrict__ idx) {
  __shared__ int m[512];
  int b = blockIdx.x, tid = threadIdx.x;
  m[tid] = (int)chsel[(size_t)b * 512 + tid];
  __syncthreads();
  for (int k = 2; k <= 512; k <<= 1) {
    for (int j = k >> 1; j > 0; j >>= 1) {
      int ixj = tid ^ j;
      if (ixj > tid) {
        int va = m[tid], vb2 = m[ixj];
        bool up = ((tid & k) == 0);
        if ((va > vb2) == up) { m[tid] = vb2; m[ixj] = va; }
      }
      __syncthreads();
    }
  }
  idx[b * 512 + tid] = m[tid];
}

// ---------------- K2: gather emb rows ---------------------------------------
__global__ void gather_kernel(const float* __restrict__ x, const int* __restrict__ idx,
                              float* __restrict__ emb) {
  int t = blockIdx.x * 256 + threadIdx.x;
  if (t >= NBAT * NSEL * CCH) return;
  int c = t & 31;
  int i = (t >> 5) & 511;
  int b = t >> 14;
  emb[t] = x[((size_t)b * CCH + c) * SEQL + idx[b * NSEL + i]];
}

// ---------------- K3: LN1 + QKV + rel-weight factorization ------------------
// 4 rows per block: weight re-reads for rows 2-4 hit L1.
// kbT layout (bf16): [((b*4+h)*4+dpack)*4096 + i*8 + (d&7)] -> coalesced attn loads.
__global__ __launch_bounds__(128) void qkv_kernel(
    const float* __restrict__ emb,
    const float* __restrict__ ln_g, const float* __restrict__ ln_b,
    const float* __restrict__ Wq, const float* __restrict__ Wk,
    const float* __restrict__ Wv, const float* __restrict__ Wrel,
    const float* __restrict__ rcb, const float* __restrict__ rpb,
    float* __restrict__ qc, unsigned short* __restrict__ kbT,
    unsigned short* __restrict__ vb16, float* __restrict__ wb, int layer) {
  __shared__ float qs[4][128];
  int hd = threadIdx.x;        // 0..127
  int hh = hd >> 5, d = hd & 31;
  const float* g = ln_g + layer * CCH;
  const float* bb = ln_b + layer * CCH;
  const float* wq = Wq + (size_t)layer * CCH * HDD + hd;
  const float* wk = Wk + (size_t)layer * CCH * HDD + hd;
  const float* wv = Wv + (size_t)layer * CCH * HDD + hd;
  #pragma unroll
  for (int r = 0; r < 4; ++r) {
    int row = blockIdx.x * 4 + r;          // b*512 + i
    int b = row >> 9, ii = row & 511;
    const float* e = emb + (size_t)row * CCH;
    float h[32];
    float mu = 0.f;
    #pragma unroll
    for (int c = 0; c < 32; ++c) { h[c] = e[c]; mu += h[c]; }
    mu *= (1.0f / 32.0f);
    float var = 0.f;
    #pragma unroll
    for (int c = 0; c < 32; ++c) { float dd0 = h[c] - mu; var += dd0 * dd0; }
    var *= (1.0f / 32.0f);
    float rstd = rsqrtf(var + 1e-5f);
    #pragma unroll
    for (int c = 0; c < 32; ++c) h[c] = (h[c] - mu) * rstd * g[c] + bb[c];
    float q = 0.f, kk = 0.f, vv = 0.f;
    #pragma unroll
    for (int c = 0; c < 32; ++c) {
      q += h[c] * wq[c * HDD];
      kk += h[c] * wk[c * HDD];
      vv += h[c] * wv[c * HDD];
    }
    q *= 0.17677669529663687f;   // DK^-0.5
    qs[r][hd] = q;
    qc[(size_t)row * HDD + hd] = q + rcb[(layer * NHEAD + hh) * DKD + d];
    kbT[((size_t)(b * 4 + hh) * 4 + (d >> 3)) * 4096 + (size_t)ii * 8 + (d & 7)] = f2bf(kk);
    vb16[(size_t)row * HDD + hd] = f2bf(vv);
    __syncthreads();
    if (hd < 120) {
      int h2 = hd / 30, f = hd % 30;
      const float* wr = Wrel + ((size_t)layer * 30 + f) * HDD + h2 * DKD;
      const float* rp = rpb + (layer * NHEAD + h2) * DKD;
      const float* qsh = qs[r] + h2 * DKD;
      float acc = 0.f;
      #pragma unroll
      for (int dd = 0; dd < 32; ++dd) acc += (qsh[dd] + rp[dd]) * wr[dd];
      wb[((size_t)row * NHEAD + h2) * 32 + f] = acc;   // padded stride 32
    }
  }
}

// ---------------- K4: attention (content + rel + softmax + PV) --------------
// 1024 blocks (b, h, 4 i-rows), 4 waves, 1 row/wave -> 16 waves/CU.
// k via transposed bf16 layout (coalesced 1KB loads), E bf16 (2 loads/gather),
// v bf16. p-buffer is wave-private: no __syncthreads in the body.
__global__ __launch_bounds__(256, 4) void attn_kernel(
    const float* __restrict__ qc, const unsigned short* __restrict__ kbT,
    const unsigned short* __restrict__ vb16, const float* __restrict__ wbuf,
    const unsigned short* __restrict__ E, const int* __restrict__ idx,
    float* __restrict__ ob) {
  __shared__ float pb[2048];     // 4 waves x 512 unnormalized probs
  __shared__ int idxl[512];
  int bid = blockIdx.x;
  int b = bid >> 9;
  int h = (bid >> 7) & 3;
  int i0 = (bid & 127) * 4;
  int tid = threadIdx.x;
  int wv = tid >> 6, ln = tid & 63;
  for (int i = tid; i < 512; i += 256) idxl[i] = idx[b * NSEL + i];
  __syncthreads();
  int i = i0 + wv;
  const float* qrow = qc + (size_t)(b * NSEL + i) * HDD + h * DKD;
  float q[32];
  #pragma unroll
  for (int d4 = 0; d4 < 8; ++d4) {
    float4 qv = *(const float4*)(qrow + d4 * 4);
    q[d4 * 4 + 0] = qv.x; q[d4 * 4 + 1] = qv.y;
    q[d4 * 4 + 2] = qv.z; q[d4 * 4 + 3] = qv.w;
  }
  const float* wrow = wbuf + ((size_t)(b * NSEL + i) * NHEAD + h) * 32;
  float w0[15], w1[15];
  #pragma unroll
  for (int f = 0; f < 15; ++f) { w0[f] = wrow[f]; w1[f] = wrow[15 + f]; }
  int ii = idxl[i];
  const uint4* kb4 = (const uint4*)kbT + (size_t)(b * 4 + h) * 4 * 512;
  float lg[8];
  #pragma unroll
  for (int u = 0; u < 8; ++u) {
    int j = u * 64 + ln;
    int dj = ii - idxl[j];
    float cacc = 0.f;
    #pragma unroll
    for (int dp = 0; dp < 4; ++dp) {
      uint4 kv = kb4[dp * 512 + j];
      cacc += q[dp * 8 + 0] * BFL(kv.x) + q[dp * 8 + 1] * BFH(kv.x)
            + q[dp * 8 + 2] * BFL(kv.y) + q[dp * 8 + 3] * BFH(kv.y)
            + q[dp * 8 + 4] * BFL(kv.z) + q[dp * 8 + 5] * BFH(kv.z)
            + q[dp * 8 + 6] * BFL(kv.w) + q[dp * 8 + 7] * BFH(kv.w);
    }
    int a = dj < 0 ? -dj : dj;
    const uint4* er = (const uint4*)(E + (size_t)a * 16);
    uint4 e0 = er[0], e1 = er[1];
    float r0 = BFL(e0.x) * w0[0]  + BFH(e0.x) * w0[1]
             + BFL(e0.y) * w0[2]  + BFH(e0.y) * w0[3]
             + BFL(e0.z) * w0[4]  + BFH(e0.z) * w0[5]
             + BFL(e0.w) * w0[6]  + BFH(e0.w) * w0[7]
             + BFL(e1.x) * w0[8]  + BFH(e1.x) * w0[9]
             + BFL(e1.y) * w0[10] + BFH(e1.y) * w0[11]
             + BFL(e1.z) * w0[12] + BFH(e1.z) * w0[13]
             + BFL(e1.w) * w0[14];
    float r1 = BFL(e0.x) * w1[0]  + BFH(e0.x) * w1[1]
             + BFL(e0.y) * w1[2]  + BFH(e0.y) * w1[3]
             + BFL(e0.z) * w1[4]  + BFH(e0.z) * w1[5]
             + BFL(e0.w) * w1[6]  + BFH(e0.w) * w1[7]
             + BFL(e1.x) * w1[8]  + BFH(e1.x) * w1[9]
             + BFL(e1.y) * w1[10] + BFH(e1.y) * w1[11]
             + BFL(e1.z) * w1[12] + BFH(e1.z) * w1[13]
             + BFL(e1.w) * w1[14];
    float sgn = dj > 0 ? 1.f : (dj < 0 ? -1.f : 0.f);
    lg[u] = cacc + r0 + sgn * r1;
  }
  // full-row softmax across the wave (512 logits, 8/lane)
  float m = lg[0];
  #pragma unroll
  for (int u = 1; u < 8; ++u) m = fmaxf(m, lg[u]);
  #pragma unroll
  for (int s = 1; s < 64; s <<= 1) m = fmaxf(m, __shfl_xor(m, s));
  float ssum = 0.f;
  float* pbw = pb + wv * 512;
  #pragma unroll
  for (int u = 0; u < 8; ++u) {
    float e = expf(lg[u] - m);
    ssum += e;
    pbw[u * 64 + ln] = e;
  }
  #pragma unroll
  for (int s = 1; s < 64; s <<= 1) ssum += __shfl_xor(ssum, s);
  float invs = 1.0f / ssum;
  // PV (wave-private p; compiler inserts lgkmcnt waits — no barrier needed)
  int d = ln & 31, jh = ln >> 5;
  const float* p = pbw + jh * 256;
  const unsigned short* vbase = vb16 + (size_t)(b * NSEL + jh * 256) * HDD + h * DKD + d;
  float acc = 0.f;
  #pragma unroll 8
  for (int jj = 0; jj < 256; ++jj)
    acc += p[jj] * bf2f(vbase[(size_t)jj * HDD]);
  acc += __shfl_xor(acc, 32);
  if (ln < 32)
    ob[(size_t)(b * NSEL + i) * HDD + h * DKD + d] = acc * invs;
}

// ---------------- K5: fused proj+residual+LN2+MLP+residual, 4 rows/block ----
// Weight values hoisted: each W element read once per block, reused x4 rows.
__global__ __launch_bounds__(256) void mlp_kernel(
    const float* __restrict__ ob, const float* __restrict__ Wo,
    const float* __restrict__ bo,
    const float* __restrict__ ln_g, const float* __restrict__ ln_b,
    const float* __restrict__ W1, const float* __restrict__ b1,
    const float* __restrict__ W2, const float* __restrict__ b2,
    float* __restrict__ emb, int layer) {
  __shared__ float part[4][8][32];
  __shared__ float res[4][32];
  __shared__ float hln[4][32];
  __shared__ float a1s[4][MLPD];
  int row0 = blockIdx.x * 4;
  int tid = threadIdx.x;
  int c = tid & 31, seg = tid >> 5;
  // --- attention out-projection
  const float* wo = Wo + (size_t)layer * HDD * CCH + c;
  float pacc[4] = {0.f, 0.f, 0.f, 0.f};
  #pragma unroll
  for (int k = 0; k < 16; ++k) {
    int kk = seg * 16 + k;
    float w = wo[kk * CCH];
    #pragma unroll
    for (int r = 0; r < 4; ++r)
      pacc[r] += ob[(size_t)(row0 + r) * HDD + kk] * w;
  }
  #pragma unroll
  for (int r = 0; r < 4; ++r) part[r][seg][c] = pacc[r];
  __syncthreads();
  if (tid < 128) {
    int r = tid >> 5, cc = tid & 31;
    float s = bo[layer * CCH + cc] + emb[(size_t)(row0 + r) * CCH + cc];
    #pragma unroll
    for (int sg = 0; sg < 8; ++sg) s += part[r][sg][cc];
    res[r][cc] = s;
  }
  __syncthreads();
  if (tid < 128) {
    int r = tid >> 5, cc = tid & 31;
    float mu = 0.f, s2 = 0.f;
    #pragma unroll
    for (int c2 = 0; c2 < 32; ++c2) { float v = res[r][c2]; mu += v; s2 += v * v; }
    mu *= (1.0f / 32.0f);
    float var = s2 * (1.0f / 32.0f) - mu * mu;
    float rstd = rsqrtf(var + 1e-5f);
    hln[r][cc] = (res[r][cc] - mu) * rstd * ln_g[layer * CCH + cc] + ln_b[layer * CCH + cc];
  }
  __syncthreads();
  // --- W1 + gelu: thread handles mm = tid and tid+256; W1 read once
  const float* w1 = W1 + (size_t)layer * CCH * MLPD;
  float accA[4], accB[4];
  float bA = b1[layer * MLPD + tid], bB = b1[layer * MLPD + tid + 256];
  #pragma unroll
  for (int r = 0; r < 4; ++r) { accA[r] = bA; accB[r] = bB; }
  for (int c2 = 0; c2 < 32; ++c2) {
    float wa = w1[c2 * MLPD + tid];
    float wb2 = w1[c2 * MLPD + tid + 256];
    #pragma unroll
    for (int r = 0; r < 4; ++r) {
      float hv = hln[r][c2];
      accA[r] += hv * wa;
      accB[r] += hv * wb2;
    }
  }
  #pragma unroll
  for (int r = 0; r < 4; ++r) {
    a1s[r][tid]       = 0.5f * accA[r] * (1.0f + erff(accA[r] * 0.70710678118654752f));
    a1s[r][tid + 256] = 0.5f * accB[r] * (1.0f + erff(accB[r] * 0.70710678118654752f));
  }
  __syncthreads();
  // --- W2: thread (c,seg) covers m = seg*64..+64; W2 read once
  const float* w2 = W2 + (size_t)layer * MLPD * CCH;
  float acc2[4] = {0.f, 0.f, 0.f, 0.f};
  #pragma unroll 4
  for (int mi = 0; mi < 64; ++mi) {
    int m = seg * 64 + mi;
    float w = w2[m * CCH + c];
    #pragma unroll
    for (int r = 0; r < 4; ++r) acc2[r] += a1s[r][m] * w;
  }
  __syncthreads();                    // part[] reuse
  #pragma unroll
  for (int r = 0; r < 4; ++r) part[r][seg][c] = acc2[r];
  __syncthreads();
  if (tid < 128) {
    int r = tid >> 5, cc = tid & 31;
    float s = b2[layer * CCH + cc] + res[r][cc];
    #pragma unroll
    for (int sg = 0; sg < 8; ++sg) s += part[r][sg][cc];
    emb[(size_t)(row0 + r) * CCH + cc] = s;
  }
}

// ---------------- K7: scatter back ------------------------------------------
__global__ void scatter_kernel(const float* __restrict__ emb, const int* __restrict__ idx,
                               float* __restrict__ out) {
  int t = blockIdx.x * 256 + threadIdx.x;
  if (t >= NBAT * NSEL * CCH) return;
  int c = t & 31;
  int i = (t >> 5) & 511;
  int b = t >> 14;
  out[((size_t)b * CCH + c) * SEQL + idx[b * NSEL + i]] = emb[t];
}

extern "C" void kernel_launch(void* const* d_in, const int* in_sizes, int n_in,
                              void* d_out, int out_size, void* d_ws, size_t ws_size,
                              hipStream_t stream) {
  (void)in_sizes; (void)n_in; (void)ws_size;
  const float* x_skip    = (const float*)d_in[0];
  const float* attention = (const float*)d_in[1];
  const float* ln1_g = (const float*)d_in[2];
  const float* ln1_b = (const float*)d_in[3];
  const float* Wq    = (const float*)d_in[4];
  const float* Wk    = (const float*)d_in[5];
  const float* Wv    = (const float*)d_in[6];
  const float* Wrel  = (const float*)d_in[7];
  const float* rcb   = (const float*)d_in[8];
  const float* rpb   = (const float*)d_in[9];
  const float* Wo    = (const float*)d_in[10];
  const float* bo    = (const float*)d_in[11];
  const float* ln2_g = (const float*)d_in[12];
  const float* ln2_b = (const float*)d_in[13];
  const float* W1    = (const float*)d_in[14];
  const float* b1    = (const float*)d_in[15];
  const float* W2    = (const float*)d_in[16];
  const float* b2    = (const float*)d_in[17];
  float* out = (float*)d_out;
  char* ws = (char*)d_ws;

  unsigned short* E    = (unsigned short*)(ws + 0);   // 45000*16*2 = 1,440,000
  int*      idx   = (int*)(ws + 1441792);             // 4,096
  float*    emb   = (float*)(ws + 1445888);           // 131,072
  float*    qc    = (float*)(ws + 1576960);           // 524,288
  unsigned short* kbT  = (unsigned short*)(ws + 2101248); // 262,144
  unsigned short* vb16 = (unsigned short*)(ws + 2363392); // 262,144
  float*    wb    = (float*)(ws + 2625536);           // 524,288
  float*    ob    = (float*)(ws + 3149824);           // 524,288
  unsigned* chsel = (unsigned*)(ws + 3674112);        // 4,096
  int*      hist  = (int*)(ws + 3678208);             // 1,048,576
  int*      cnt   = (int*)(ws + 4726784);             // 64
  unsigned long long* cand = (unsigned long long*)(ws + 4726848); // 65,536
  int*      thr   = (int*)(ws + 4792384);             // 64  -> total ~4.8 MB

  hipMemsetAsync(d_out, 0, (size_t)out_size * sizeof(float), stream);
  hipMemsetAsync(ws + 3678208, 0, 1048576 + 64, stream);   // hist + cnt
  build_etab_kernel<<<(SEQL + 255) / 256, 256, 0, stream>>>(E);
  topk_hist_kernel<<<4 * TKB, 256, 0, stream>>>(attention, hist);
  topk_thresh_kernel<<<4, 1024, 0, stream>>>(hist, thr);
  topk_collect_kernel<<<4 * TKB, 256, 0, stream>>>(attention, thr, cand, cnt);
  topk_sort_kernel<<<4, 1024, 0, stream>>>(cand, cnt, chsel);
  topk_merge_kernel<<<2, 512, 0, stream>>>(chsel, idx);
  gather_kernel<<<128, 256, 0, stream>>>(x_skip, idx, emb);
  for (int l = 0; l < 4; ++l) {
    qkv_kernel<<<256, 128, 0, stream>>>(emb, ln1_g, ln1_b, Wq, Wk, Wv,
                                        Wrel, rcb, rpb, qc, kbT, vb16, wb, l);
    attn_kernel<<<1024, 256, 0, stream>>>(qc, kbT, vb16, wb, E, idx, ob);
    mlp_kernel<<<256, 256, 0, stream>>>(ob, Wo, bo, ln2_g, ln2_b,
                                        W1, b1, W2, b2, emb, l);
  }
  scatter_kernel<<<128, 256, 0, stream>>>(emb, idx, out);
}